// Round 8
// baseline (360.589 us; speedup 1.0000x reference)
//
#include <hip/hip_runtime.h>

#define NSEQ  1024
#define NHEAD 12
#define HDIM  64
#define CDIM  768
#define BATCH 8

typedef short bf16x8 __attribute__((ext_vector_type(8)));
typedef float f32x4  __attribute__((ext_vector_type(4)));

__device__ __forceinline__ float bf2f(unsigned short h) {
  unsigned u = ((unsigned)h) << 16;
  float f;
  __builtin_memcpy(&f, &u, 4);
  return f;
}
__device__ __forceinline__ unsigned short f2bf(float f) {   // RNE
  unsigned u;
  __builtin_memcpy(&u, &f, 4);
  u = (u + 0x7fffu + ((u >> 16) & 1u)) >> 16;
  return (unsigned short)u;
}
__device__ __forceinline__ unsigned short f2bf_rz(float f) { // truncate (1 op)
  unsigned u;
  __builtin_memcpy(&u, &f, 4);
  return (unsigned short)(u >> 16);
}

// Fragment-major offsets: every attention-side load = base + lane*8 ushorts (16B).
__device__ __forceinline__ size_t qk_off(size_t bh, int s, int d) {
  return ((((bh * 64 + (s >> 4)) * 2 + (d >> 5)) * 64) + (((d >> 3) & 3) * 16) + (s & 15)) * 8 + (d & 7);
}
__device__ __forceinline__ size_t v_off(size_t bh, int key, int d) {
  return ((((bh * 4 + (d >> 4)) * 32 + (key >> 5)) * 64) + (((key >> 3) & 3) * 16) + (d & 15)) * 8 + (key & 7);
}

// async global->LDS, 16B per lane; data lands at ldsbase + lane*16
#define GLD16(GP, LP) __builtin_amdgcn_global_load_lds( \
    (const __attribute__((address_space(1))) void*)(GP), \
    (__attribute__((address_space(3))) void*)(LP), 16, 0, 0)

// ---------------- fp32 -> bf16 hi/lo conversion pre-pass ----------------
__global__ __launch_bounds__(256)
void convert_kernel(const float* __restrict__ x, const float* __restrict__ w_in,
                    const float* __restrict__ w_out,
                    unsigned short* __restrict__ xh, unsigned short* __restrict__ xl,
                    unsigned short* __restrict__ wih, unsigned short* __restrict__ wil,
                    unsigned short* __restrict__ woh)
{
  const int idx = (blockIdx.x * 256 + threadIdx.x) * 4;
  if (idx < 6291456) {
    float4 v = *(const float4*)(x + idx);
    ushort4 h, l;
    h.x = f2bf(v.x); l.x = f2bf(v.x - bf2f(h.x));
    h.y = f2bf(v.y); l.y = f2bf(v.y - bf2f(h.y));
    h.z = f2bf(v.z); l.z = f2bf(v.z - bf2f(h.z));
    h.w = f2bf(v.w); l.w = f2bf(v.w - bf2f(h.w));
    *(ushort4*)(xh + idx) = h;
    *(ushort4*)(xl + idx) = l;
  } else if (idx < 6291456 + 1769472) {
    const int j = idx - 6291456;
    float4 v = *(const float4*)(w_in + j);
    ushort4 h, l;
    h.x = f2bf(v.x); l.x = f2bf(v.x - bf2f(h.x));
    h.y = f2bf(v.y); l.y = f2bf(v.y - bf2f(h.y));
    h.z = f2bf(v.z); l.z = f2bf(v.z - bf2f(h.z));
    h.w = f2bf(v.w); l.w = f2bf(v.w - bf2f(h.w));
    *(ushort4*)(wih + j) = h;
    *(ushort4*)(wil + j) = l;
  } else {
    const int j = idx - 8060928;
    float4 v = *(const float4*)(w_out + j);
    ushort4 h;
    h.x = f2bf(v.x); h.y = f2bf(v.y); h.z = f2bf(v.z); h.w = f2bf(v.w);
    *(ushort4*)(woh + j) = h;
  }
}

// ---------------- MFMA GEMM: C[M,N] = A[M,768] @ B[N,768]^T ----------------
// Stacked-K hi/lo: K' = 2304 = [Ah.Bh | Al.Bh | Ah.Bl] -> fp32-grade product.
// XCD-aware 1D grid: xcd = id&7 owns bm band [xcd*8, xcd*8+8); bm_local fast.
template<int MODE>
__global__ __launch_bounds__(256)
void gemm_mfma(const unsigned short* __restrict__ Ah, const unsigned short* __restrict__ Al,
               const unsigned short* __restrict__ Bh, const unsigned short* __restrict__ Bl,
               float* __restrict__ Cout,
               unsigned short* __restrict__ Qfh, unsigned short* __restrict__ Qfl,
               unsigned short* __restrict__ Kfh, unsigned short* __restrict__ Kfl,
               unsigned short* __restrict__ Vf)
{
  __shared__ unsigned short Asm[128][64];
  __shared__ unsigned short Bsm[128][64];
  const int t    = threadIdx.x;
  const int lane = t & 63;
  const int wid  = t >> 6;
  const int c    = lane & 15;
  const int g    = lane >> 4;
  const int id   = blockIdx.x;
  const int xcd  = id & 7;
  const int j    = id >> 3;
  const int bm   = (j & 7) + xcd * 8;
  const int bn   = j >> 3;
  const int sec    = (MODE == 0) ? (bn / 6) : 0;
  const int nsteps = (MODE == 0 && sec < 2) ? 36 : 12;

  f32x4 acc[4][4];
#pragma unroll
  for (int mi = 0; mi < 4; ++mi)
#pragma unroll
    for (int ni = 0; ni < 4; ++ni) acc[mi][ni] = (f32x4){0.f, 0.f, 0.f, 0.f};

  const size_t Am0 = (size_t)bm * 128;
  const size_t Bn0 = (size_t)bn * 128;
  const int srow = wid * 32 + (lane >> 3);
  const int scol = (lane & 7) * 8;
  const int mh = (wid & 1) * 64;
  const int nh = (wid >> 1) * 64;

  for (int ks = 0; ks < nsteps; ++ks) {
    const int ksec = (ks >= 24) ? 2 : ((ks >= 12) ? 1 : 0);
    const int kin  = (ks - ksec * 12) * 64;
    const unsigned short* Asrc = (ksec == 1) ? Al : Ah;
    const unsigned short* Bsrc = (ksec == 2) ? Bl : Bh;
    __syncthreads();
#pragma unroll
    for (int i = 0; i < 4; ++i) {
      GLD16(Asrc + (Am0 + srow + i * 8) * 768 + kin + scol, &Asm[wid * 32 + i * 8][0]);
      GLD16(Bsrc + (Bn0 + srow + i * 8) * 768 + kin + scol, &Bsm[wid * 32 + i * 8][0]);
    }
    __syncthreads();
#pragma unroll
    for (int kk = 0; kk < 2; ++kk) {
      bf16x8 a[4], bb[4];
#pragma unroll
      for (int mi = 0; mi < 4; ++mi)
        a[mi] = *(const bf16x8*)&Asm[mh + mi * 16 + c][kk * 32 + g * 8];
#pragma unroll
      for (int ni = 0; ni < 4; ++ni)
        bb[ni] = *(const bf16x8*)&Bsm[nh + ni * 16 + c][kk * 32 + g * 8];
#pragma unroll
      for (int mi = 0; mi < 4; ++mi)
#pragma unroll
        for (int ni = 0; ni < 4; ++ni)
          acc[mi][ni] = __builtin_amdgcn_mfma_f32_16x16x32_bf16(a[mi], bb[ni], acc[mi][ni], 0, 0, 0);
    }
  }

  if (MODE == 1) {
#pragma unroll
    for (int mi = 0; mi < 4; ++mi) {
#pragma unroll
      for (int r = 0; r < 4; ++r) {
        const int m = bm * 128 + mh + mi * 16 + g * 4 + r;
#pragma unroll
        for (int ni = 0; ni < 4; ++ni) {
          const int n = bn * 128 + nh + ni * 16 + c;
          Cout[(size_t)m * 768 + n] = acc[mi][ni][r];
        }
      }
    }
  } else {
#pragma unroll
    for (int mi = 0; mi < 4; ++mi) {
#pragma unroll
      for (int r = 0; r < 4; ++r) {
        const int m   = bm * 128 + mh + mi * 16 + g * 4 + r;
        const int bi  = m >> 10;
        const int qi  = m & 1023;
#pragma unroll
        for (int ni = 0; ni < 4; ++ni) {
          const int n  = bn * 128 + nh + ni * 16 + c;
          const int np = n - sec * 768;
          const int h  = np >> 6;
          const int d  = np & 63;
          const size_t bh = (size_t)(bi * 12 + h);
          float v = acc[mi][ni][r];
          if (sec == 0) {
            v *= 0.125f;                      // pre-scale q by 1/sqrt(64)
            size_t off = qk_off(bh, qi, d);
            unsigned short hi = f2bf_rz(v);   // truncation: hi/lo residual stays exact
            Qfh[off] = hi;
            Qfl[off] = f2bf_rz(v - bf2f(hi));
          } else if (sec == 1) {
            size_t off = qk_off(bh, qi, d);
            unsigned short hi = f2bf_rz(v);
            Kfh[off] = hi;
            Kfl[off] = f2bf_rz(v - bf2f(hi));
          } else {
            Vf[v_off(bh, qi, d)] = f2bf(v);   // RNE: single-pass, avoid bias
          }
        }
      }
    }
  }
}

// ---------------- fused MFMA attention + importance ----------------
// 512 threads = 8 waves; wave w owns keys [w*128, w*128+128). 16 waves/CU.
// P rows stride 1028 ushorts (514 dw = 2 mod 8: b16 writes conflict-free).
// Cpart overlaid into each wave's private P column slice (16x128 ushort = 16x64 f32).
struct AttnSmem {
  union {
    unsigned short Pu[16][1028];  // bf16 probs of current head
    float AW[8][1028];            // head-mean attn, one 8-row half at a time
  } u;                            // 32,896 B
  float red[16][8];               // cross-wave exp-sum
};

__global__ __launch_bounds__(512, 4)
void attn_mfma(const unsigned short* __restrict__ Qfh, const unsigned short* __restrict__ Qfl,
               const unsigned short* __restrict__ Kfh, const unsigned short* __restrict__ Kfl,
               const unsigned short* __restrict__ Vf,
               unsigned short* __restrict__ CtxG, float* __restrict__ Imp)
{
  __shared__ AttnSmem sm;
  const int t    = threadIdx.x;
  const int lane = t & 63;
  const int wid  = t >> 6;       // 0..7: key slice
  const int g    = lane >> 4;
  const int c    = lane & 15;
  const int b    = blockIdx.x & 7;    // XCD-affinity swizzle
  const int qt   = blockIdx.x >> 3;
  const int q0   = qt * 16;

  float aw[8][4];
#pragma unroll
  for (int kt = 0; kt < 8; ++kt)
#pragma unroll
    for (int r = 0; r < 4; ++r) aw[kt][r] = 0.f;

  for (int h = 0; h < 12; ++h) {
    const size_t bh = (size_t)b * 12 + h;

    const size_t qbase = ((bh * 64 + qt) * 2) * 512 + lane * 8;
    bf16x8 qh0 = *(const bf16x8*)(Qfh + qbase);
    bf16x8 qh1 = *(const bf16x8*)(Qfh + qbase + 512);
    bf16x8 ql0 = *(const bf16x8*)(Qfl + qbase);
    bf16x8 ql1 = *(const bf16x8*)(Qfl + qbase + 512);

    // ---- S = Q K^T over this wave's 128 keys ----
    f32x4 acc[8];
#pragma unroll
    for (int kt = 0; kt < 8; ++kt) acc[kt] = (f32x4){0.f, 0.f, 0.f, 0.f};
    const size_t kbase = ((bh * 64 + wid * 8) * 2) * 512 + lane * 8;
#pragma unroll
    for (int kt = 0; kt < 8; ++kt) {
      const size_t kb = kbase + (size_t)kt * 1024;
      bf16x8 kh0 = *(const bf16x8*)(Kfh + kb);
      bf16x8 kh1 = *(const bf16x8*)(Kfh + kb + 512);
      bf16x8 kl0 = *(const bf16x8*)(Kfl + kb);
      bf16x8 kl1 = *(const bf16x8*)(Kfl + kb + 512);
      f32x4 a = acc[kt];
      a = __builtin_amdgcn_mfma_f32_16x16x32_bf16(qh0, kh0, a, 0, 0, 0);
      a = __builtin_amdgcn_mfma_f32_16x16x32_bf16(qh1, kh1, a, 0, 0, 0);
      a = __builtin_amdgcn_mfma_f32_16x16x32_bf16(qh0, kl0, a, 0, 0, 0);
      a = __builtin_amdgcn_mfma_f32_16x16x32_bf16(qh1, kl1, a, 0, 0, 0);
      a = __builtin_amdgcn_mfma_f32_16x16x32_bf16(ql0, kh0, a, 0, 0, 0);
      a = __builtin_amdgcn_mfma_f32_16x16x32_bf16(ql1, kh1, a, 0, 0, 0);
      acc[kt] = a;
    }

    // ---- uncentered softmax: exp + cross-wave (8) sum ----
    float sume[4];
#pragma unroll
    for (int r = 0; r < 4; ++r) {
      float s = 0.f;
#pragma unroll
      for (int kt = 0; kt < 8; ++kt) {
        float e = __expf(fminf(acc[kt][r], 80.f));
        acc[kt][r] = e;
        s += e;
      }
      s += __shfl_xor(s, 1);
      s += __shfl_xor(s, 2);
      s += __shfl_xor(s, 4);
      s += __shfl_xor(s, 8);
      sume[r] = s;
    }
    if (c == 0) {
#pragma unroll
      for (int r = 0; r < 4; ++r) sm.red[g * 4 + r][wid] = sume[r];
    }
    __syncthreads();
#pragma unroll
    for (int r = 0; r < 4; ++r) {
      const float* rp = sm.red[g * 4 + r];
      float tot = ((rp[0] + rp[1]) + (rp[2] + rp[3])) +
                  ((rp[4] + rp[5]) + (rp[6] + rp[7]));
      float inv = 1.f / tot;
#pragma unroll
      for (int kt = 0; kt < 8; ++kt) {
        float p = acc[kt][r] * inv;
        aw[kt][r] += p * (1.f / 12.f);
        sm.u.Pu[g * 4 + r][wid * 128 + kt * 16 + c] = f2bf_rz(p);
      }
    }
    // no barrier: wave reads back only its own P columns below

    // ---- ctx partial: P[16 x 128] @ V^T ----
    f32x4 cacc[4];
#pragma unroll
    for (int dt = 0; dt < 4; ++dt) cacc[dt] = (f32x4){0.f, 0.f, 0.f, 0.f};
#pragma unroll
    for (int ks = 0; ks < 4; ++ks) {
      bf16x8 pf = *(const bf16x8*)&sm.u.Pu[c][wid * 128 + ks * 32 + g * 8];
#pragma unroll
      for (int dt = 0; dt < 4; ++dt) {
        bf16x8 vf = *(const bf16x8*)(Vf + (((size_t)(bh * 4 + dt)) * 32 + wid * 4 + ks) * 512 + lane * 8);
        cacc[dt] = __builtin_amdgcn_mfma_f32_16x16x32_bf16(pf, vf, cacc[dt], 0, 0, 0);
      }
    }
    // Cpart into own P slice (wave-private; all own pf reads precede in program order)
#pragma unroll
    for (int dt = 0; dt < 4; ++dt) {
#pragma unroll
      for (int r = 0; r < 4; ++r) {
        float* cw = (float*)&sm.u.Pu[g * 4 + r][wid * 128];
        cw[dt * 16 + c] = cacc[dt][r];
      }
    }
    __syncthreads();
    for (int i = t; i < 1024; i += 512) {
      int qi = i >> 6, d = i & 63;
      const float* cf = (const float*)&sm.u.Pu[qi][0];
      float s = 0.f;
#pragma unroll
      for (int w = 0; w < 8; ++w) s += cf[w * 64 + d];
      CtxG[((size_t)(b * 1024 + q0 + qi)) * 768 + h * 64 + d] = f2bf(s);
    }
    __syncthreads();   // protect pool before next head's P writes
  }

  // ---- importance from head-mean attention, two 8-row halves ----
  float ia[2] = {0.f, 0.f};
#pragma unroll
  for (int half = 0; half < 2; ++half) {
    if ((g >> 1) == half) {
#pragma unroll
      for (int kt = 0; kt < 8; ++kt)
#pragma unroll
        for (int r = 0; r < 4; ++r)
          sm.u.AW[(g & 1) * 4 + r][wid * 128 + kt * 16 + c] = aw[kt][r];
    }
    __syncthreads();
#pragma unroll
    for (int qi = 0; qi < 8; ++qi) {
#pragma unroll
      for (int cc = 0; cc < 2; ++cc) {
        int k = t * 2 + cc;
        float am = sm.u.AW[qi][k == 0 ? 0 : k - 1];
        float ap = sm.u.AW[qi][k == 1023 ? 1023 : k + 1];
        ia[cc] += fabsf((ap - am) * 0.5f);
      }
    }
    __syncthreads();
  }
#pragma unroll
  for (int cc = 0; cc < 2; ++cc)
    atomicAdd(&Imp[b * 1024 + t * 2 + cc], ia[cc]);
}

// ---------------- conv3 + standardize + softmax(fs/0.1) ----------------
__device__ inline float blk_sum(float v, volatile float* wbuf, int t) {
#pragma unroll
  for (int off = 32; off > 0; off >>= 1) v += __shfl_xor(v, off);
  __syncthreads();
  if ((t & 63) == 0) wbuf[t >> 6] = v;
  __syncthreads();
  return (wbuf[0] + wbuf[1]) + (wbuf[2] + wbuf[3]);
}
__device__ inline float blk_max(float v, volatile float* wbuf, int t) {
#pragma unroll
  for (int off = 32; off > 0; off >>= 1) v = fmaxf(v, __shfl_xor(v, off));
  __syncthreads();
  if ((t & 63) == 0) wbuf[t >> 6] = v;
  __syncthreads();
  return fmaxf(fmaxf(wbuf[0], wbuf[1]), fmaxf(wbuf[2], wbuf[3]));
}

__global__ __launch_bounds__(256)
void scores_kernel(const float* __restrict__ Imp, const float* __restrict__ smw,
                   float* __restrict__ Out)
{
  __shared__ float ip[1026];
  __shared__ float wbuf[4];
  const int b = blockIdx.x;
  const int t = threadIdx.x;

  if (t == 0) { ip[0] = 0.f; ip[1025] = 0.f; }
  float4 iv = *(const float4*)(Imp + (size_t)b * 1024 + t * 4);
  ip[1 + t * 4 + 0] = iv.x;
  ip[1 + t * 4 + 1] = iv.y;
  ip[1 + t * 4 + 2] = iv.z;
  ip[1 + t * 4 + 3] = iv.w;
  __syncthreads();

  const float w0 = smw[0], w1 = smw[1], w2 = smw[2];
  float smv[4];
#pragma unroll
  for (int j = 0; j < 4; ++j) {
    int k = t * 4 + j;
    smv[j] = w0 * ip[k] + w1 * ip[k + 1] + w2 * ip[k + 2];
  }
  float tot = blk_sum((smv[0] + smv[1]) + (smv[2] + smv[3]), wbuf, t);
  float mu  = tot * (1.f / 1024.f);
  float lv = 0.f;
#pragma unroll
  for (int j = 0; j < 4; ++j) { float d = smv[j] - mu; lv += d * d; }
  float var = blk_sum(lv, wbuf, t) * (1.f / 1023.f);
  float inv = 1.f / (sqrtf(var) + 1e-6f);
  float fs[4];
#pragma unroll
  for (int j = 0; j < 4; ++j) fs[j] = (smv[j] - mu) * inv * 10.f;
  float M = blk_max(fmaxf(fmaxf(fs[0], fs[1]), fmaxf(fs[2], fs[3])), wbuf, t);
  float e[4]; float ls = 0.f;
#pragma unroll
  for (int j = 0; j < 4; ++j) { e[j] = __expf(fs[j] - M); ls += e[j]; }
  float S = blk_sum(ls, wbuf, t);
  float r = 1.f / S;
  float4 o = {e[0] * r, e[1] * r, e[2] * r, e[3] * r};
  *(float4*)(Out + (size_t)b * 1024 + t * 4) = o;
}

extern "C" void kernel_launch(void* const* d_in, const int* in_sizes, int n_in,
                              void* d_out, int out_size, void* d_ws, size_t ws_size,
                              hipStream_t stream)
{
  const float* x     = (const float*)d_in[0];
  const float* w_in  = (const float*)d_in[1];
  const float* w_out = (const float*)d_in[2];
  const float* smw   = (const float*)d_in[3];
  float* out = (float*)d_out;

  const size_t SZx  = 6291456;   // 8192*768
  const size_t SZw  = 1769472;   // 2304*768
  const size_t SZwo = 589824;    // 768*768

  unsigned short* xh   = (unsigned short*)d_ws;
  unsigned short* xl   = xh + SZx;
  unsigned short* wih  = xl + SZx;
  unsigned short* wil  = wih + SZw;
  unsigned short* woh  = wil + SZw;
  unsigned short* qfh  = woh + SZwo;
  unsigned short* qfl  = qfh + SZx;
  unsigned short* kfh  = qfl + SZx;
  unsigned short* kfl  = kfh + SZx;
  unsigned short* vf   = kfl + SZx;
  unsigned short* ctxb = vf + SZx;
  float* imp = (float*)(ctxb + SZx);

  hipMemsetAsync(imp, 0, BATCH * NSEQ * sizeof(float), stream);

  convert_kernel<<<8448, 256, 0, stream>>>(x, w_in, w_out, xh, xl, wih, wil, woh);
  gemm_mfma<0><<<1152, 256, 0, stream>>>(xh, xl, wih, wil, nullptr,
                                         qfh, qfl, kfh, kfl, vf);
  attn_mfma<<<512, 512, 0, stream>>>(qfh, qfl, kfh, kfl, vf, ctxb, imp);
  gemm_mfma<1><<<384, 256, 0, stream>>>(ctxb, nullptr, woh, nullptr, out,
                                        nullptr, nullptr, nullptr, nullptr, nullptr);
  scores_kernel<<<8, 256, 0, stream>>>(imp, smw, out + SZx);
}